// Round 18
// baseline (2345.851 us; speedup 1.0000x reference)
//
#include <hip/hip_runtime.h>
#include <hip/hip_bf16.h>

// GlobalLocalAttention on MI355X — BK=32 conv8 (64KB LDS -> 2 blocks/CU for
// cross-block LDS/MFMA overlap; same 4-phase snake, halved per-tile counts).
// Regions: A=[0,64MiB) x_t -> dwt ; B=[64,160MiB) qkvh(per-batch) -> outsum ;
//          C=[160,224MiB) local(bf16) -> dw_nchw(bf16) ; W=weights (~1.7MB).
// d_out doubles as the bf16 attention-output scratch (final GEMM rewrites it).

typedef __bf16 bf16x8 __attribute__((ext_vector_type(8)));
typedef float  f32x4  __attribute__((ext_vector_type(4)));
typedef unsigned short u16;

#define HWPIX 65536
#define NPIX  131072

__device__ __forceinline__ u16 f2bf(float f) {
    union { float f; unsigned u; } v; v.f = f;
    return (u16)((v.u + 0x7fffu + ((v.u >> 16) & 1u)) >> 16);
}
__device__ __forceinline__ float bf2f(u16 h) {
    union { unsigned u; float f; } v; v.u = ((unsigned)h) << 16;
    return v.f;
}

#define GLDS16(gp, lp) __builtin_amdgcn_global_load_lds( \
    (__attribute__((address_space(1))) void*)(gp), \
    (__attribute__((address_space(3))) void*)(lp), 16, 0, 0)

template <int V> struct IC { static constexpr int value = V; };

__device__ __forceinline__ void unp8(uint4 u, float* f) {
    f[0] = bf2f((u16)(u.x & 0xffff)); f[1] = bf2f((u16)(u.x >> 16));
    f[2] = bf2f((u16)(u.y & 0xffff)); f[3] = bf2f((u16)(u.y >> 16));
    f[4] = bf2f((u16)(u.z & 0xffff)); f[5] = bf2f((u16)(u.z >> 16));
    f[6] = bf2f((u16)(u.w & 0xffff)); f[7] = bf2f((u16)(u.w >> 16));
}

// ---------------------------------------------------------------------------
__global__ void prep_weights(const float* __restrict__ w_qkv,
                             const float* __restrict__ w_l1,
                             const float* __restrict__ bn1g, const float* __restrict__ bn1b,
                             const float* __restrict__ w_l2,
                             const float* __restrict__ bn2g, const float* __restrict__ bn2b,
                             const float* __restrict__ w_pw,
                             const float* __restrict__ bn3g, const float* __restrict__ bn3b,
                             u16* __restrict__ wl, u16* __restrict__ wq, u16* __restrict__ wpw,
                             float* __restrict__ bias_l, float* __restrict__ bias_pw,
                             u16* __restrict__ zeros)
{
    const int tid = threadIdx.x;
    if (blockIdx.x >= 256) {
        int row = blockIdx.x - 256;              // 0..767
        wq[row * 256 + tid] = f2bf(w_qkv[row * 256 + tid]);
        return;
    }
    const int oc = blockIdx.x, ic = tid;
    const float rs = rsqrtf(1.f + 1e-5f);
    const float s1 = bn1g[oc] * rs;
    const float s2 = bn2g[oc] * rs;
    const float w2v = w_l2[oc * 256 + ic] * s2;
    #pragma unroll
    for (int tap = 0; tap < 9; ++tap) {
        float v = s1 * w_l1[(oc * 256 + ic) * 9 + tap];
        if (tap == 4) v += w2v;
        wl[oc * 2304 + tap * 256 + ic] = f2bf(v);
    }
    const float s3 = bn3g[ic] * rs;
    const float wp = w_pw[oc * 256 + ic];
    wpw[oc * 256 + ic] = f2bf(wp * s3);

    __shared__ float red[256];
    red[ic] = wp * bn3b[ic];
    __syncthreads();
    for (int s = 128; s > 0; s >>= 1) {
        if (ic < s) red[ic] += red[ic + s];
        __syncthreads();
    }
    if (ic == 0) {
        bias_pw[oc] = red[0];
        bias_l[oc]  = bn1b[oc] + bn2b[oc];
    }
    if (blockIdx.x == 0) zeros[tid] = 0;
}

// ---------------------------------------------------------------------------
// NCHW f32 -> channels-last bf16, float4-vectorized staging.
__global__ __launch_bounds__(256)
void to_chlast_f32(const float* __restrict__ in, u16* __restrict__ out)
{
    __shared__ float L[32][65];
    const int tid = threadIdx.x;
    const int p0 = blockIdx.x * 64;
    const int b = p0 >> 16, pin = p0 & 65535;
    const float* src = in + (size_t)b * 256 * HWPIX + pin;
    for (int cb = 0; cb < 256; cb += 32) {
        #pragma unroll
        for (int e = 0; e < 2; ++e) {
            const int idx = e * 256 + tid;        // 512 float4 chunks
            const int row = idx >> 4, ch = idx & 15;
            const float4 v = *(const float4*)(src + (size_t)(cb + row) * HWPIX + ch * 4);
            L[row][ch * 4 + 0] = v.x; L[row][ch * 4 + 1] = v.y;
            L[row][ch * 4 + 2] = v.z; L[row][ch * 4 + 3] = v.w;
        }
        __syncthreads();
        const int px = tid >> 2, cq = tid & 3;
        u16 t[8];
        #pragma unroll
        for (int e = 0; e < 8; ++e) t[e] = f2bf(L[cq * 8 + e][px]);
        uint4 v;
        v.x = (unsigned)t[0] | ((unsigned)t[1] << 16);
        v.y = (unsigned)t[2] | ((unsigned)t[3] << 16);
        v.z = (unsigned)t[4] | ((unsigned)t[5] << 16);
        v.w = (unsigned)t[6] | ((unsigned)t[7] << 16);
        *(uint4*)(out + (size_t)(p0 + px) * 256 + cb + cq * 8) = v;
        __syncthreads();
    }
}

// NCHW bf16 -> channels-last bf16, 16B-chunk staging.
__global__ __launch_bounds__(256)
void to_chlast_bf16(const u16* __restrict__ in, u16* __restrict__ out)
{
    __shared__ float L[32][65];
    const int tid = threadIdx.x;
    const int p0 = blockIdx.x * 64;
    const int b = p0 >> 16, pin = p0 & 65535;
    const u16* src = in + (size_t)b * 256 * HWPIX + pin;
    for (int cb = 0; cb < 256; cb += 32) {
        {
            const int row = tid >> 3, ch = tid & 7;   // 256 chunks of 8 bf16
            const uint4 u = *(const uint4*)(src + (size_t)(cb + row) * HWPIX + ch * 8);
            float f[8]; unp8(u, f);
            #pragma unroll
            for (int e = 0; e < 8; ++e) L[row][ch * 8 + e] = f[e];
        }
        __syncthreads();
        const int px = tid >> 2, cq = tid & 3;
        u16 t[8];
        #pragma unroll
        for (int e = 0; e < 8; ++e) t[e] = f2bf(L[cq * 8 + e][px]);
        uint4 v;
        v.x = (unsigned)t[0] | ((unsigned)t[1] << 16);
        v.y = (unsigned)t[2] | ((unsigned)t[3] << 16);
        v.z = (unsigned)t[4] | ((unsigned)t[5] << 16);
        v.w = (unsigned)t[6] | ((unsigned)t[7] << 16);
        *(uint4*)(out + (size_t)(p0 + px) * 256 + cb + cq * 8) = v;
        __syncthreads();
    }
}

// ---------------------------------------------------------------------------
// 4-phase 256x256 implicit-GEMM conv, BK=32 (64KB LDS -> 2 blocks/CU).
// Per K-tile: 12 ds_read_b128 + 32 MFMA + 4 GLDS; snake quadrant order with
// fragment reuse; XOR swizzle phys = chunk ^ (r&3) ^ ((r>>2)&3) (2-way = free);
// counted vmcnt(2); setprio; raw s_barrier; XCD block swizzle.
// A-rows offset by blockIdx.y*256; QKV_MODE: per-batch [768][65536] output.
template <int NTAPS, bool OUT_BF16, bool HAS_BIAS, bool QKV_MODE>
__global__ __launch_bounds__(512, 4)
void conv8(const u16* __restrict__ X, const u16* __restrict__ Wm,
           const float* __restrict__ bias, void* __restrict__ outv,
           const u16* __restrict__ zeros, int px_origin)
{
    constexpr int NT = NTAPS * 8;        // K-tiles of 32
    constexpr int KTOT = NTAPS * 256;
    __shared__ __align__(16) u16 SA[2][256 * 32];   // 16KB each
    __shared__ __align__(16) u16 SB[2][256 * 32];

    const int tid  = threadIdx.x;
    const int wv   = tid >> 6, lane = tid & 63;
    const int wr   = wv >> 2, wc = wv & 3;       // 2M x 4N wave grid
    const int lr   = lane & 15, lh = lane >> 4;
    const int bswz = (blockIdx.x & 7) * (gridDim.x >> 3) + (blockIdx.x >> 3);
    const int pbase = px_origin + bswz * 256;    // 256 px = one image row
    const int obase = blockIdx.y * 256;

    f32x4 acc[2][2][4][2];
    #pragma unroll
    for (int a = 0; a < 2; ++a)
        #pragma unroll
        for (int b = 0; b < 2; ++b)
            #pragma unroll
            for (int m = 0; m < 4; ++m)
                #pragma unroll
                for (int n = 0; n < 2; ++n)
                    acc[a][b][m][n] = (f32x4){0.f, 0.f, 0.f, 0.f};

    // staging: halftile = 128 rows x 32k = 8KB = 512 lanes x 16B (1 GLDS/thread).
    // dest linear (lane's row = rowbase + (lane>>2), chunk = lane&3); source
    // chunk inverse-swizzled: csrc = (lane&3) ^ swz(row), swz(r)=(r&3)^((r>>2)&3).
    auto stageA = [&](u16* dstbuf, int j, int h) {
        const int tap = j >> 3, kc = j & 7;
        const int rowbase = h * 128 + wv * 16;
        const int row = obase + rowbase + (lane >> 2);
        const int csrc = (lane & 3) ^ ((lane >> 2) & 3) ^ ((lane >> 4) & 3);
        GLDS16(Wm + (size_t)row * KTOT + tap * 256 + kc * 32 + csrc * 8,
               dstbuf + rowbase * 32);
    };
    auto stageB = [&](u16* dstbuf, int j, int h) {
        const int tap = j >> 3, kc = j & 7;
        int dy = 0, dx = 0;
        if (NTAPS == 9) { const int t3 = (tap * 11) >> 5; dy = t3 - 1; dx = tap - t3 * 3 - 1; }
        const int h0 = (pbase & 65535) >> 8;
        const bool hok = (NTAPS == 1) || ((unsigned)(h0 + dy) < 256u);
        const int rowbase = h * 128 + wv * 16;
        const int r = rowbase + (lane >> 2);       // w coordinate
        const int csrc = (lane & 3) ^ ((lane >> 2) & 3) ^ ((lane >> 4) & 3);
        const int wp = r + dx;
        const u16* src = (hok && (unsigned)wp < 256u)
            ? X + (size_t)(pbase + dy * 256 + dx + r) * 256 + kc * 32 + csrc * 8
            : zeros + csrc * 8;
        GLDS16(src, dstbuf + rowbase * 32);
    };

    // fragment reads: row bits 0-3 = lr; phys = lh ^ (lr&3) ^ ((lr>>2)&3)
    auto loadA = [&](bf16x8 (&af)[4], const u16* Ab, int MH) {
        #pragma unroll
        for (int m = 0; m < 4; ++m) {
            const int row = MH * 128 + wr * 64 + m * 16 + lr;
            const int phys = lh ^ (lr & 3) ^ ((lr >> 2) & 3);
            af[m] = *(const bf16x8*)&Ab[row * 32 + phys * 8];
        }
    };
    auto loadB = [&](bf16x8 (&bv)[2], const u16* Bb, int NH) {
        #pragma unroll
        for (int n = 0; n < 2; ++n) {
            const int row = NH * 128 + wc * 32 + n * 16 + lr;
            const int phys = lh ^ (lr & 3) ^ ((lr >> 2) & 3);
            bv[n] = *(const bf16x8*)&Bb[row * 32 + phys * 8];
        }
    };
    auto mfma8 = [&](auto MHc, auto NHc, bf16x8 (&af)[4], bf16x8 (&bv)[2]) {
        constexpr int MH = decltype(MHc)::value;
        constexpr int NH = decltype(NHc)::value;
        __builtin_amdgcn_s_setprio(1);
        #pragma unroll
        for (int m = 0; m < 4; ++m)
            #pragma unroll
            for (int n = 0; n < 2; ++n)
                acc[MH][NH][m][n] = __builtin_amdgcn_mfma_f32_16x16x32_bf16(
                    af[m], bv[n], acc[MH][NH][m][n], 0, 0, 0);
        __builtin_amdgcn_s_setprio(0);
    };

    // prologue: tile0 fully + Ah0[1]/Bh1[1] (the "t-1 ph3" loads)
    stageA(SA[0], 0, 0); stageA(SA[0], 0, 1);
    stageB(SB[0], 0, 0); stageB(SB[0], 0, 1);
    if (NT > 1) { stageA(SA[1], 1, 0); stageB(SB[1], 1, 1); }
    asm volatile("s_waitcnt vmcnt(2)" ::: "memory");
    __builtin_amdgcn_s_barrier();

    for (int t = 0; t < NT; ++t) {
        const u16* Ab = SA[t & 1];
        const u16* Bb = SB[t & 1];
        u16* SAn = SA[(t + 1) & 1]; u16* SBn = SB[(t + 1) & 1];
        u16* SAc = SA[t & 1];       u16* SBc = SB[t & 1];
        const bool g1 = (t + 1 < NT), g2 = (t + 2 < NT);
        bf16x8 afr[4], a1r[4], bf0[2], bf1[2];

        // ph0: Q(0,0) — read A0 + B0; stage Ah1[t+1]
        loadA(afr, Ab, 0); loadB(bf0, Bb, 0);
        if (g1) stageA(SAn, t + 1, 1);
        __builtin_amdgcn_s_barrier();
        asm volatile("s_waitcnt lgkmcnt(0)" ::: "memory");
        mfma8(IC<0>{}, IC<0>{}, afr, bf0);
        __builtin_amdgcn_s_barrier();

        // ph1: Q(0,1) — reuse A0, read B1; stage Bh0[t+1]
        loadB(bf1, Bb, 1);
        if (g1) stageB(SBn, t + 1, 0);
        __builtin_amdgcn_s_barrier();
        asm volatile("s_waitcnt lgkmcnt(0)" ::: "memory");
        mfma8(IC<0>{}, IC<1>{}, afr, bf1);
        __builtin_amdgcn_s_barrier();

        // ph2: Q(1,1) — read A1, reuse B1
        loadA(a1r, Ab, 1);
        __builtin_amdgcn_s_barrier();
        asm volatile("s_waitcnt lgkmcnt(0)" ::: "memory");
        mfma8(IC<1>{}, IC<1>{}, a1r, bf1);
        __builtin_amdgcn_s_barrier();

        // ph3: Q(1,0) — reuse A1 + B0 (no ds_reads); stage Ah0/Bh1[t+2] into
        // current buffer; vmcnt(2) leaves only them in flight.
        if (g2) { stageA(SAc, t + 2, 0); stageB(SBc, t + 2, 1); }
        __builtin_amdgcn_s_barrier();
        if (g2) asm volatile("s_waitcnt vmcnt(2)" ::: "memory");
        else    asm volatile("s_waitcnt vmcnt(0)" ::: "memory");
        mfma8(IC<1>{}, IC<0>{}, a1r, bf0);
        __builtin_amdgcn_s_barrier();
    }

    #pragma unroll
    for (int mh = 0; mh < 2; ++mh)
        #pragma unroll
        for (int m = 0; m < 4; ++m) {
            const int oc = mh * 128 + wr * 64 + m * 16 + lh * 4;
            #pragma unroll
            for (int nh = 0; nh < 2; ++nh)
                #pragma unroll
                for (int n = 0; n < 2; ++n) {
                    const int px = pbase + nh * 128 + wc * 32 + n * 16 + lr;
                    const int pin = px & 65535;
                    #pragma unroll
                    for (int r = 0; r < 4; ++r) {
                        float v = acc[mh][nh][m][n][r];
                        if (HAS_BIAS) v += bias[oc + r];
                        size_t idx;
                        if (QKV_MODE)
                            idx = (size_t)(obase + oc + r) * HWPIX + pin;
                        else
                            idx = ((size_t)((px >> 16) * 256 + oc + r)) * HWPIX + pin;
                        if (OUT_BF16) ((u16*)outv)[idx] = f2bf(v);
                        else          ((float*)outv)[idx] = v;
                    }
                }
        }
}

// ---------------------------------------------------------------------------
// MFMA windowed attention (verified round 11), per-batch qkv buffer
// [768][65536] bf16; i1 full [0,32); batch passed for output indexing.
__global__ __launch_bounds__(256, 2)
void attn_mfma(const u16* __restrict__ qkvh,
               const float* __restrict__ rpb,
               u16* __restrict__ outb, int batch)
{
    __shared__ __align__(16) u16 stg[3 * 64 * 64];
    __shared__ __align__(16) u16 Pl[4][64][68];
    __shared__ float rpl[900];
    __shared__ float linv[4][64];
    __shared__ __align__(16) u16 zlds[8];

    const int bid = blockIdx.x;            // 4096 = 1024 windows x 4 head-quads
    const int hq  = bid & 3;
    const int mw  = bid >> 2;              // 0..1023
    const int i1  = mw >> 5, i3 = mw & 31;
    const int tid = threadIdx.x;
    const int wv  = tid >> 6, lane = tid & 63;
    const int l15 = lane & 15, l4 = lane >> 4;
    const size_t base = (size_t)i1 * 1572864 + (size_t)i3 * 6144 + (size_t)hq * 64;

    #pragma unroll
    for (int it = 0; it < 6; ++it) {
        const int id = it * 256 + tid;
        const int s = id >> 9, tok = (id >> 3) & 63, cd = id & 7;
        const int csrc = cd ^ (tok & 7);
        const int i2 = tok >> 3, i4 = tok & 7;
        const u16* src = qkvh + base + (size_t)i2 * 196608 + (size_t)i4 * 768 +
                         s * 256 + csrc * 8;
        GLDS16(src, &stg[(it * 256 + wv * 64) * 8]);
    }
    for (int i = tid; i < 900; i += 256)
        rpl[i] = rpb[(i >> 2) * 16 + hq * 4 + (i & 3)];
    if (tid < 8) zlds[tid] = 0;
    __syncthreads();

    f32x4 acc[4][4];
    #pragma unroll
    for (int kt = 0; kt < 4; ++kt)
        #pragma unroll
        for (int qt = 0; qt < 4; ++qt)
            acc[kt][qt] = (f32x4){0.f, 0.f, 0.f, 0.f};

    bf16x8 ka[4], qb[4];
    #pragma unroll
    for (int kt = 0; kt < 4; ++kt) {
        const int tok = kt * 16 + l15;
        const int phys = (2 * wv + l4) ^ (tok & 7);
        const u16* p = (l4 < 2) ? &stg[(64 + tok) * 64 + phys * 8] : zlds;
        ka[kt] = *(const bf16x8*)p;
    }
    #pragma unroll
    for (int qt = 0; qt < 4; ++qt) {
        const int tok = qt * 16 + l15;
        const int phys = (2 * wv + l4) ^ (tok & 7);
        const u16* p = (l4 < 2) ? &stg[tok * 64 + phys * 8] : zlds;
        qb[qt] = *(const bf16x8*)p;
    }
    #pragma unroll
    for (int kt = 0; kt < 4; ++kt)
        #pragma unroll
        for (int qt = 0; qt < 4; ++qt)
            acc[kt][qt] = __builtin_amdgcn_mfma_f32_16x16x32_bf16(
                ka[kt], qb[qt], acc[kt][qt], 0, 0, 0);

    #pragma unroll
    for (int qt = 0; qt < 4; ++qt) {
        const int q = qt * 16 + l15;
        const int base_q = ((q >> 3) + 7) * 15 + (q & 7) + 7;
        #pragma unroll
        for (int kt = 0; kt < 4; ++kt) {
            const int koff = kt * 30 + (l4 >> 1) * 15 + (l4 & 1) * 4;
            #pragma unroll
            for (int r = 0; r < 4; ++r)
                acc[kt][qt][r] = acc[kt][qt][r] * 0.25f +
                                 rpl[(base_q - koff - r) * 4 + wv];
        }
        float mx = -1e30f;
        #pragma unroll
        for (int kt = 0; kt < 4; ++kt)
            #pragma unroll
            for (int r = 0; r < 4; ++r)
                mx = fmaxf(mx, acc[kt][qt][r]);
        mx = fmaxf(mx, __shfl_xor(mx, 16));
        mx = fmaxf(mx, __shfl_xor(mx, 32));
        float l = 0.f;
        #pragma unroll
        for (int kt = 0; kt < 4; ++kt)
            #pragma unroll
            for (int r = 0; r < 4; ++r) {
                const float p = __expf(acc[kt][qt][r] - mx);
                acc[kt][qt][r] = p;
                l += p;
            }
        l += __shfl_xor(l, 16);
        l += __shfl_xor(l, 32);
        if (l4 == 0) linv[wv][q] = 1.f / l;
        #pragma unroll
        for (int kt = 0; kt < 4; ++kt) {
            const int ku = kt * 16 + l4 * 4;
            const unsigned w0 = (unsigned)f2bf(acc[kt][qt][0]) |
                                ((unsigned)f2bf(acc[kt][qt][1]) << 16);
            const unsigned w1 = (unsigned)f2bf(acc[kt][qt][2]) |
                                ((unsigned)f2bf(acc[kt][qt][3]) << 16);
            *(unsigned*)&Pl[wv][q][ku]     = w0;
            *(unsigned*)&Pl[wv][q][ku + 2] = w1;
        }
    }

    f32x4 oac[4];
    #pragma unroll
    for (int qt = 0; qt < 4; ++qt) oac[qt] = (f32x4){0.f, 0.f, 0.f, 0.f};

    #pragma unroll
    for (int ks = 0; ks < 2; ++ks) {
        bf16x8 vf;
        #pragma unroll
        for (int e = 0; e < 8; ++e) {
            const int tok = ks * 32 + l4 * 8 + e;
            const int phys = (2 * wv + (l15 >> 3)) ^ e;
            vf[e] = *(const __bf16*)&stg[(128 + tok) * 64 + phys * 8 + (l15 & 7)];
        }
        #pragma unroll
        for (int qt = 0; qt < 4; ++qt) {
            const int q = qt * 16 + l15;
            const uint2 a  = *(const uint2*)&Pl[wv][q][ks * 32 + l4 * 8];
            const uint2 b2 = *(const uint2*)&Pl[wv][q][ks * 32 + l4 * 8 + 4];
            uint4 t4; t4.x = a.x; t4.y = a.y; t4.z = b2.x; t4.w = b2.y;
            const bf16x8 pf = *(const bf16x8*)&t4;
            oac[qt] = __builtin_amdgcn_mfma_f32_16x16x32_bf16(pf, vf, oac[qt], 0, 0, 0);
        }
    }

    const int head = hq * 4 + wv;
    const int n = batch * 1024 + i1 * 32 + i3;
    u16* op = outb + ((size_t)(n * 16 + head) << 10);
    #pragma unroll
    for (int qt = 0; qt < 4; ++qt)
        #pragma unroll
        for (int r = 0; r < 4; ++r) {
            const int q = qt * 16 + l4 * 4 + r;
            op[q * 16 + l15] = f2bf(oac[qt][r] * linv[wv][q]);
        }
}

// ---------------------------------------------------------------------------
// Staging helper: load 39x71 ext tile (ext: 256->254, outside->0) into LDS
// with vectorized interior (39x8 uint4 chunks) + scalar 7-col halo.
template <int STRIDE>
__device__ __forceinline__ void stage_ext_tile(const u16* __restrict__ A,
                                               float (*S)[STRIDE],
                                               int TH, int TW, int tid)
{
    for (int idx = tid; idx < 312; idx += 256) {
        const int i = idx >> 3, ch = idx & 7;
        const int gh = TH + i - 3;
        const int eh = (gh == 256) ? 254 : gh;
        float f[8];
        if ((unsigned)eh < 256u) {
            const uint4 u = *(const uint4*)(A + eh * 256 + TW + ch * 8);
            unp8(u, f);
        } else {
            #pragma unroll
            for (int e = 0; e < 8; ++e) f[e] = 0.f;
        }
        #pragma unroll
        for (int e = 0; e < 8; ++e) S[i][3 + ch * 8 + e] = f[e];
    }
    for (int idx = tid; idx < 273; idx += 256) {
        const int i = idx / 7, jj = idx - i * 7;
        const int j = (jj < 3) ? jj : jj + 64;
        const int gh = TH + i - 3, gw = TW + j - 3;
        const int eh = (gh == 256) ? 254 : gh;
        const int ew = (gw == 256) ? 254 : gw;
        float v = 0.f;
        if ((unsigned)eh < 256u && (unsigned)ew < 256u) v = bf2f(A[eh * 256 + ew]);
        S[i][j] = v;
    }
}

// ---------------------------------------------------------------------------
// pool_add2: outsum = 0.125*(V8+H8)(attn_ext) + local, one 32x64 tile/block.
__global__ __launch_bounds__(256)
void pool_add2(const u16* __restrict__ attn,
               const u16* __restrict__ local,
               u16* __restrict__ outsum)
{
    __shared__ float Sa[39][73];
    __shared__ float Sv[32][65];

    const int bid   = blockIdx.x;
    const int plane = bid >> 5;
    const int tile  = bid & 31;
    const int TH    = (tile >> 2) * 32;
    const int TW    = (tile & 3) * 64;
    const int tid   = threadIdx.x;
    const u16* A    = attn + (size_t)plane * HWPIX;

    stage_ext_tile<73>(A, Sa, TH, TW, tid);
    __syncthreads();

    {
        const int c = tid & 63, g = tid >> 6;
        float s = 0.f;
        #pragma unroll
        for (int t = 0; t < 8; ++t) s += Sa[8 * g + t][c + 3];
        #pragma unroll
        for (int q = 0; q < 8; ++q) {
            Sv[8 * g + q][c] = s;
            if (q < 7) s += Sa[8 * g + q + 8][c + 3] - Sa[8 * g + q][c + 3];
        }
    }
    __syncthreads();

    {
        const int r = tid >> 3, cb = tid & 7;
        float h = 0.f;
        #pragma unroll
        for (int t = 0; t < 8; ++t) h += Sa[r + 3][8 * cb + t];
        const uint4 lv = *(const uint4*)(local + (size_t)plane * HWPIX +
                                         (TH + r) * 256 + TW + 8 * cb);
        float lf[8];
        unp8(lv, lf);
        u16 res[8];
        #pragma unroll
        for (int q = 0; q < 8; ++q) {
            const int ox = 8 * cb + q;
            res[q] = f2bf(0.125f * (Sv[r][ox] + h) + lf[q]);
            if (q < 7) h += Sa[r + 3][ox + 8] - Sa[r + 3][ox];
        }
        uint4 pk;
        pk.x = (unsigned)res[0] | ((unsigned)res[1] << 16);
        pk.y = (unsigned)res[2] | ((unsigned)res[3] << 16);
        pk.z = (unsigned)res[4] | ((unsigned)res[5] << 16);
        pk.w = (unsigned)res[6] | ((unsigned)res[7] << 16);
        *(uint4*)(outsum + (size_t)plane * HWPIX + (TH + r) * 256 + TW + 8 * cb) = pk;
    }
}

// ---------------------------------------------------------------------------
// dwconv3: reflect(0,1)+zero-pad(3) + depthwise 8x8, register-blocked 2x4.
__global__ __launch_bounds__(256)
void dwconv3(const u16* __restrict__ outsum, const float* __restrict__ wdw,
             u16* __restrict__ dwo)
{
    __shared__ __align__(16) float Sp[39][76];
    __shared__ float wk[64];

    const int bid   = blockIdx.x;
    const int plane = bid >> 5;
    const int c     = plane & 255;
    const int tile  = bid & 31;
    const int TH    = (tile >> 2) * 32;
    const int TW    = (tile & 3) * 64;
    const int tid   = threadIdx.x;
    const u16* A    = outsum + (size_t)plane * HWPIX;

    if (tid < 64) wk[tid] = wdw[c * 64 + tid];

    stage_ext_tile<76>(A, Sp, TH, TW, tid);
    __syncthreads();

    float wreg[64];
    #pragma unroll
    for (int i = 0; i < 64; ++i) wreg[i] = wk[i];

    const int rb = tid >> 4;
    const int cb = tid & 15;
    const int oy2 = rb * 2, ox4 = cb * 4;
    float acc[2][4];
    #pragma unroll
    for (int q = 0; q < 2; ++q)
        #pragma unroll
        for (int j = 0; j < 4; ++j) acc[q][j] = 0.f;

    #pragma unroll
    for (int r = 0; r < 9; ++r) {
        const float4 ra  = *(const float4*)&Sp[oy2 + r][ox4];
        const float4 rb4 = *(const float4*)&Sp[oy2 + r][ox4 + 4];
        const float4 rc  = *(const float4*)&Sp[oy2 + r][ox4 + 8];
        const float row[12] = {ra.x, ra.y, ra.z, ra.w, rb4.x, rb4.y, rb4.z, rb4.w,
                               rc.x, rc.y, rc.z, rc.w};
        #pragma unroll
        for (int q = 0; q < 2; ++q) {
            const int kh = r - q;
            if (kh >= 0 && kh < 8) {
                #pragma unroll
                for (int kw = 0; kw < 8; ++kw) {
                    const float w = wreg[kh * 8 + kw];
                    #pragma unroll
                    for (int j = 0; j < 4; ++j)
                        acc[q][j] += w * row[j + kw];
                }
            }
        }
    }
    u16* O = dwo + (size_t)plane * HWPIX;
    #pragma unroll
    for (int q = 0; q < 2; ++q) {
        ushort4 pk;
        pk.x = f2bf(acc[q][0]); pk.y = f2bf(acc[q][1]);
        pk.z = f2bf(acc[q][2]); pk.w = f2bf(acc[q][3]);
        *(ushort4*)&O[(TH + oy2 + q) * 256 + TW + ox4] = pk;
    }
}

// ---------------------------------------------------------------------------
extern "C" void kernel_launch(void* const* d_in, const int* in_sizes, int n_in,
                              void* d_out, int out_size, void* d_ws, size_t ws_size,
                              hipStream_t stream)
{
    const float* x     = (const float*)d_in[0];
    const float* w_qkv = (const float*)d_in[1];
    const float* w_l1  = (const float*)d_in[2];
    const float* bn1g  = (const float*)d_in[3];
    const float* bn1b  = (const float*)d_in[4];
    const float* w_l2  = (const float*)d_in[5];
    const float* bn2g  = (const float*)d_in[6];
    const float* bn2b  = (const float*)d_in[7];
    const float* w_dw  = (const float*)d_in[8];
    const float* bn3g  = (const float*)d_in[9];
    const float* bn3b  = (const float*)d_in[10];
    const float* w_pw  = (const float*)d_in[11];
    const float* rpb   = (const float*)d_in[12];
    float* out = (float*)d_out;
    char* ws = (char*)d_ws;

    if (ws_size < (size_t)236587520) return;

    u16* x_t = (u16*)(ws + 0);
    u16* dwt = (u16*)(ws + 0);
    u16* qkvh   = (u16*)(ws + 67108864);     // per-batch [768][65536] bf16 = 96MiB
    u16* outsum = (u16*)(ws + 67108864);
    u16* localb  = (u16*)(ws + 167772160);
    u16* dw_nchw = (u16*)(ws + 167772160);
    u16*   wl      = (u16*)(ws + 234881024);
    u16*   wq      = (u16*)(ws + 236060672);
    u16*   wpw     = (u16*)(ws + 236453888);
    float* bias_l  = (float*)(ws + 236584960);
    float* bias_pw = (float*)(ws + 236585984);
    u16*   zeros   = (u16*)(ws + 236587008);
    u16* attnb = (u16*)d_out;              // d_out as bf16 attn scratch

    prep_weights<<<1024, 256, 0, stream>>>(w_qkv, w_l1, bn1g, bn1b, w_l2, bn2g, bn2b,
                                           w_pw, bn3g, bn3b, wl, wq, wpw, bias_l, bias_pw, zeros);
    to_chlast_f32<<<NPIX / 64, 256, 0, stream>>>(x, x_t);
    // conv3x3 + bias
    conv8<9, true, true, false><<<dim3(NPIX / 256, 1), 512, 0, stream>>>(
        x_t, wl, bias_l, localb, zeros, 0);
    // qkv batch 0 -> attention batch 0
    conv8<1, true, false, true><<<dim3(HWPIX / 256, 3), 512, 0, stream>>>(
        x_t, wq, nullptr, qkvh, zeros, 0);
    attn_mfma<<<4096, 256, 0, stream>>>(qkvh, rpb, attnb, 0);
    // qkv batch 1 -> attention batch 1
    conv8<1, true, false, true><<<dim3(HWPIX / 256, 3), 512, 0, stream>>>(
        x_t, wq, nullptr, qkvh, zeros, HWPIX);
    attn_mfma<<<4096, 256, 0, stream>>>(qkvh, rpb, attnb, 1);
    // pools + local add -> bf16 outsum (overwrites qkv region)
    pool_add2<<<16384, 256, 0, stream>>>(attnb, localb, outsum);
    dwconv3<<<16384, 256, 0, stream>>>(outsum, w_dw, dw_nchw);
    to_chlast_bf16<<<NPIX / 64, 256, 0, stream>>>(dw_nchw, dwt);
    // pointwise + bias -> final f32 output
    conv8<1, false, true, false><<<dim3(NPIX / 256, 1), 512, 0, stream>>>(
        dwt, wpw, bias_pw, out, zeros, 0);
}

// Round 19
// 628.432 us; speedup vs baseline: 3.7329x; 3.7329x over previous
//
#include <hip/hip_runtime.h>
#include <hip/hip_bf16.h>

// GlobalLocalAttention on MI355X — REVERT to round-17 best-known (629 us).
// qkv on the 4-phase conv8 GEMM via batch-split; BK=64, 128KB LDS.
// Regions: A=[0,64MiB) x_t -> dwt ; B=[64,160MiB) qkvh(per-batch) -> outsum ;
//          C=[160,224MiB) local(bf16) -> dw_nchw(bf16) ; W=weights (~1.7MB).
// d_out doubles as the bf16 attention-output scratch (final GEMM rewrites it).

typedef __bf16 bf16x8 __attribute__((ext_vector_type(8)));
typedef float  f32x4  __attribute__((ext_vector_type(4)));
typedef unsigned short u16;

#define HWPIX 65536
#define NPIX  131072

__device__ __forceinline__ u16 f2bf(float f) {
    union { float f; unsigned u; } v; v.f = f;
    return (u16)((v.u + 0x7fffu + ((v.u >> 16) & 1u)) >> 16);
}
__device__ __forceinline__ float bf2f(u16 h) {
    union { unsigned u; float f; } v; v.u = ((unsigned)h) << 16;
    return v.f;
}

#define GLDS16(gp, lp) __builtin_amdgcn_global_load_lds( \
    (__attribute__((address_space(1))) void*)(gp), \
    (__attribute__((address_space(3))) void*)(lp), 16, 0, 0)

template <int V> struct IC { static constexpr int value = V; };

__device__ __forceinline__ void unp8(uint4 u, float* f) {
    f[0] = bf2f((u16)(u.x & 0xffff)); f[1] = bf2f((u16)(u.x >> 16));
    f[2] = bf2f((u16)(u.y & 0xffff)); f[3] = bf2f((u16)(u.y >> 16));
    f[4] = bf2f((u16)(u.z & 0xffff)); f[5] = bf2f((u16)(u.z >> 16));
    f[6] = bf2f((u16)(u.w & 0xffff)); f[7] = bf2f((u16)(u.w >> 16));
}

// ---------------------------------------------------------------------------
__global__ void prep_weights(const float* __restrict__ w_qkv,
                             const float* __restrict__ w_l1,
                             const float* __restrict__ bn1g, const float* __restrict__ bn1b,
                             const float* __restrict__ w_l2,
                             const float* __restrict__ bn2g, const float* __restrict__ bn2b,
                             const float* __restrict__ w_pw,
                             const float* __restrict__ bn3g, const float* __restrict__ bn3b,
                             u16* __restrict__ wl, u16* __restrict__ wq, u16* __restrict__ wpw,
                             float* __restrict__ bias_l, float* __restrict__ bias_pw,
                             u16* __restrict__ zeros)
{
    const int tid = threadIdx.x;
    if (blockIdx.x >= 256) {
        int row = blockIdx.x - 256;              // 0..767
        wq[row * 256 + tid] = f2bf(w_qkv[row * 256 + tid]);
        return;
    }
    const int oc = blockIdx.x, ic = tid;
    const float rs = rsqrtf(1.f + 1e-5f);
    const float s1 = bn1g[oc] * rs;
    const float s2 = bn2g[oc] * rs;
    const float w2v = w_l2[oc * 256 + ic] * s2;
    #pragma unroll
    for (int tap = 0; tap < 9; ++tap) {
        float v = s1 * w_l1[(oc * 256 + ic) * 9 + tap];
        if (tap == 4) v += w2v;
        wl[oc * 2304 + tap * 256 + ic] = f2bf(v);
    }
    const float s3 = bn3g[ic] * rs;
    const float wp = w_pw[oc * 256 + ic];
    wpw[oc * 256 + ic] = f2bf(wp * s3);

    __shared__ float red[256];
    red[ic] = wp * bn3b[ic];
    __syncthreads();
    for (int s = 128; s > 0; s >>= 1) {
        if (ic < s) red[ic] += red[ic + s];
        __syncthreads();
    }
    if (ic == 0) {
        bias_pw[oc] = red[0];
        bias_l[oc]  = bn1b[oc] + bn2b[oc];
    }
    if (blockIdx.x == 0) zeros[tid] = 0;
}

// ---------------------------------------------------------------------------
// NCHW f32 -> channels-last bf16, float4-vectorized staging.
__global__ __launch_bounds__(256)
void to_chlast_f32(const float* __restrict__ in, u16* __restrict__ out)
{
    __shared__ float L[32][65];
    const int tid = threadIdx.x;
    const int p0 = blockIdx.x * 64;
    const int b = p0 >> 16, pin = p0 & 65535;
    const float* src = in + (size_t)b * 256 * HWPIX + pin;
    for (int cb = 0; cb < 256; cb += 32) {
        #pragma unroll
        for (int e = 0; e < 2; ++e) {
            const int idx = e * 256 + tid;        // 512 float4 chunks
            const int row = idx >> 4, ch = idx & 15;
            const float4 v = *(const float4*)(src + (size_t)(cb + row) * HWPIX + ch * 4);
            L[row][ch * 4 + 0] = v.x; L[row][ch * 4 + 1] = v.y;
            L[row][ch * 4 + 2] = v.z; L[row][ch * 4 + 3] = v.w;
        }
        __syncthreads();
        const int px = tid >> 2, cq = tid & 3;
        u16 t[8];
        #pragma unroll
        for (int e = 0; e < 8; ++e) t[e] = f2bf(L[cq * 8 + e][px]);
        uint4 v;
        v.x = (unsigned)t[0] | ((unsigned)t[1] << 16);
        v.y = (unsigned)t[2] | ((unsigned)t[3] << 16);
        v.z = (unsigned)t[4] | ((unsigned)t[5] << 16);
        v.w = (unsigned)t[6] | ((unsigned)t[7] << 16);
        *(uint4*)(out + (size_t)(p0 + px) * 256 + cb + cq * 8) = v;
        __syncthreads();
    }
}

// NCHW bf16 -> channels-last bf16, 16B-chunk staging.
__global__ __launch_bounds__(256)
void to_chlast_bf16(const u16* __restrict__ in, u16* __restrict__ out)
{
    __shared__ float L[32][65];
    const int tid = threadIdx.x;
    const int p0 = blockIdx.x * 64;
    const int b = p0 >> 16, pin = p0 & 65535;
    const u16* src = in + (size_t)b * 256 * HWPIX + pin;
    for (int cb = 0; cb < 256; cb += 32) {
        {
            const int row = tid >> 3, ch = tid & 7;   // 256 chunks of 8 bf16
            const uint4 u = *(const uint4*)(src + (size_t)(cb + row) * HWPIX + ch * 8);
            float f[8]; unp8(u, f);
            #pragma unroll
            for (int e = 0; e < 8; ++e) L[row][ch * 8 + e] = f[e];
        }
        __syncthreads();
        const int px = tid >> 2, cq = tid & 3;
        u16 t[8];
        #pragma unroll
        for (int e = 0; e < 8; ++e) t[e] = f2bf(L[cq * 8 + e][px]);
        uint4 v;
        v.x = (unsigned)t[0] | ((unsigned)t[1] << 16);
        v.y = (unsigned)t[2] | ((unsigned)t[3] << 16);
        v.z = (unsigned)t[4] | ((unsigned)t[5] << 16);
        v.w = (unsigned)t[6] | ((unsigned)t[7] << 16);
        *(uint4*)(out + (size_t)(p0 + px) * 256 + cb + cq * 8) = v;
        __syncthreads();
    }
}

// ---------------------------------------------------------------------------
// 4-phase 256x256 implicit-GEMM conv (round-13 verified): 16x16x32 MFMA,
// snake quadrant order with fragment reuse, BK=64, 8 waves, 128KB LDS, XOR
// swizzle (0 conflicts), counted vmcnt(4), setprio, raw s_barrier, XCD block
// swizzle. A-rows offset by blockIdx.y*256 (qkv weight is 768x256).
// QKV_MODE: output plane = oc directly into a per-batch [768][65536] buffer;
// px_origin selects the batch's pixel range.
template <int NTAPS, bool OUT_BF16, bool HAS_BIAS, bool QKV_MODE>
__global__ __launch_bounds__(512, 2)
void conv8(const u16* __restrict__ X, const u16* __restrict__ Wm,
           const float* __restrict__ bias, void* __restrict__ outv,
           const u16* __restrict__ zeros, int px_origin)
{
    constexpr int NT = NTAPS * 4;        // K-tiles of 64
    constexpr int KTOT = NTAPS * 256;
    __shared__ __align__(16) u16 SA[2][256 * 64];
    __shared__ __align__(16) u16 SB[2][256 * 64];

    const int tid  = threadIdx.x;
    const int wv   = tid >> 6, lane = tid & 63;
    const int wr   = wv >> 2, wc = wv & 3;       // 2M x 4N wave grid
    const int lr   = lane & 15, lh = lane >> 4;
    const int bswz = (blockIdx.x & 7) * (gridDim.x >> 3) + (blockIdx.x >> 3);
    const int pbase = px_origin + bswz * 256;    // 256 px = one image row
    const int obase = blockIdx.y * 256;

    f32x4 acc[2][2][4][2];
    #pragma unroll
    for (int a = 0; a < 2; ++a)
        #pragma unroll
        for (int b = 0; b < 2; ++b)
            #pragma unroll
            for (int m = 0; m < 4; ++m)
                #pragma unroll
                for (int n = 0; n < 2; ++n)
                    acc[a][b][m][n] = (f32x4){0.f, 0.f, 0.f, 0.f};

    auto stageA = [&](u16* dstbuf, int j, int h) {
        const int tap = j >> 2, kc = j & 3;
        #pragma unroll
        for (int c = 0; c < 2; ++c) {
            const int rowbase = h * 128 + wv * 16 + c * 8;
            const int row = obase + rowbase + (lane >> 3);
            const int csrc = (lane & 7) ^ (lane >> 3);
            GLDS16(Wm + (size_t)row * KTOT + tap * 256 + kc * 64 + csrc * 8,
                   dstbuf + rowbase * 64);
        }
    };
    auto stageB = [&](u16* dstbuf, int j, int h) {
        const int tap = j >> 2, kc = j & 3;
        int dy = 0, dx = 0;
        if (NTAPS == 9) { const int t3 = (tap * 11) >> 5; dy = t3 - 1; dx = tap - t3 * 3 - 1; }
        const int h0 = (pbase & 65535) >> 8;
        const bool hok = (NTAPS == 1) || ((unsigned)(h0 + dy) < 256u);
        #pragma unroll
        for (int c = 0; c < 2; ++c) {
            const int rowbase = h * 128 + wv * 16 + c * 8;
            const int r = rowbase + (lane >> 3);       // w coordinate
            const int csrc = (lane & 7) ^ (lane >> 3);
            const int wp = r + dx;
            const u16* src = (hok && (unsigned)wp < 256u)
                ? X + (size_t)(pbase + dy * 256 + dx + r) * 256 + kc * 64 + csrc * 8
                : zeros + (lane & 7) * 16;
            GLDS16(src, dstbuf + rowbase * 64);
        }
    };

    auto loadA = [&](bf16x8 (&af)[4][2], const u16* Ab, int MH) {
        #pragma unroll
        for (int m = 0; m < 4; ++m)
            #pragma unroll
            for (int kk = 0; kk < 2; ++kk) {
                const int row = MH * 128 + wr * 64 + m * 16 + lr;
                const int phys = (kk * 4 + lh) ^ (lr & 7);
                af[m][kk] = *(const bf16x8*)&Ab[row * 64 + phys * 8];
            }
    };
    auto loadB = [&](bf16x8 (&bv)[2][2], const u16* Bb, int NH) {
        #pragma unroll
        for (int n = 0; n < 2; ++n)
            #pragma unroll
            for (int kk = 0; kk < 2; ++kk) {
                const int row = NH * 128 + wc * 32 + n * 16 + lr;
                const int phys = (kk * 4 + lh) ^ (lr & 7);
                bv[n][kk] = *(const bf16x8*)&Bb[row * 64 + phys * 8];
            }
    };
    auto mfma16 = [&](auto MHc, auto NHc, bf16x8 (&af)[4][2], bf16x8 (&bv)[2][2]) {
        constexpr int MH = decltype(MHc)::value;
        constexpr int NH = decltype(NHc)::value;
        __builtin_amdgcn_s_setprio(1);
        #pragma unroll
        for (int m = 0; m < 4; ++m)
            #pragma unroll
            for (int n = 0; n < 2; ++n) {
                acc[MH][NH][m][n] = __builtin_amdgcn_mfma_f32_16x16x32_bf16(
                    af[m][0], bv[n][0], acc[MH][NH][m][n], 0, 0, 0);
                acc[MH][NH][m][n] = __builtin_amdgcn_mfma_f32_16x16x32_bf16(
                    af[m][1], bv[n][1], acc[MH][NH][m][n], 0, 0, 0);
            }
        __builtin_amdgcn_s_setprio(0);
    };

    // prologue: tile0 fully + Ah0[1]/Bh1[1] (the "t-1 ph3" loads)
    stageA(SA[0], 0, 0); stageA(SA[0], 0, 1);
    stageB(SB[0], 0, 0); stageB(SB[0], 0, 1);
    if (NT > 1) { stageA(SA[1], 1, 0); stageB(SB[1], 1, 1); }
    asm volatile("s_waitcnt vmcnt(4)" ::: "memory");
    __builtin_amdgcn_s_barrier();

    for (int t = 0; t < NT; ++t) {
        const u16* Ab = SA[t & 1];
        const u16* Bb = SB[t & 1];
        u16* SAn = SA[(t + 1) & 1]; u16* SBn = SB[(t + 1) & 1];
        u16* SAc = SA[t & 1];       u16* SBc = SB[t & 1];
        const bool g1 = (t + 1 < NT), g2 = (t + 2 < NT);
        bf16x8 afr[4][2], a1r[4][2], bf0[2][2], bf1[2][2];

        // ph0: Q(0,0) — read A0 + B0; stage Ah1[t+1]
        loadA(afr, Ab, 0); loadB(bf0, Bb, 0);
        if (g1) stageA(SAn, t + 1, 1);
        __builtin_amdgcn_s_barrier();
        asm volatile("s_waitcnt lgkmcnt(0)" ::: "memory");
        mfma16(IC<0>{}, IC<0>{}, afr, bf0);
        __builtin_amdgcn_s_barrier();

        // ph1: Q(0,1) — reuse A0, read B1; stage Bh0[t+1]
        loadB(bf1, Bb, 1);
        if (g1) stageB(SBn, t + 1, 0);
        __builtin_amdgcn_s_barrier();
        asm volatile("s_waitcnt lgkmcnt(0)" ::: "memory");
        mfma16(IC<0>{}, IC<1>{}, afr, bf1);
        __builtin_amdgcn_s_barrier();

        // ph2: Q(1,1) — read A1, reuse B1
        loadA(a1r, Ab, 1);
        __builtin_amdgcn_s_barrier();
        asm volatile("s_waitcnt lgkmcnt(0)" ::: "memory");
        mfma16(IC<1>{}, IC<1>{}, a1r, bf1);
        __builtin_amdgcn_s_barrier();

        // ph3: Q(1,0) — reuse A1 + B0 (no ds_reads); stage Ah0/Bh1[t+2] into
        // current buffer; vmcnt(4) leaves only them in flight.
        if (g2) { stageA(SAc, t + 2, 0); stageB(SBc, t + 2, 1); }
        __builtin_amdgcn_s_barrier();
        if (g2) asm volatile("s_waitcnt vmcnt(4)" ::: "memory");
        else    asm volatile("s_waitcnt vmcnt(0)" ::: "memory");
        mfma16(IC<1>{}, IC<0>{}, a1r, bf0);
        __builtin_amdgcn_s_barrier();
    }

    #pragma unroll
    for (int mh = 0; mh < 2; ++mh)
        #pragma unroll
        for (int m = 0; m < 4; ++m) {
            const int oc = mh * 128 + wr * 64 + m * 16 + lh * 4;
            #pragma unroll
            for (int nh = 0; nh < 2; ++nh)
                #pragma unroll
                for (int n = 0; n < 2; ++n) {
                    const int px = pbase + nh * 128 + wc * 32 + n * 16 + lr;
                    const int pin = px & 65535;
                    #pragma unroll
                    for (int r = 0; r < 4; ++r) {
                        float v = acc[mh][nh][m][n][r];
                        if (HAS_BIAS) v += bias[oc + r];
                        size_t idx;
                        if (QKV_MODE)
                            idx = (size_t)(obase + oc + r) * HWPIX + pin;
                        else
                            idx = ((size_t)((px >> 16) * 256 + oc + r)) * HWPIX + pin;
                        if (OUT_BF16) ((u16*)outv)[idx] = f2bf(v);
                        else          ((float*)outv)[idx] = v;
                    }
                }
        }
}

// ---------------------------------------------------------------------------
// MFMA windowed attention (verified round 11), per-batch qkv buffer
// [768][65536] bf16; i1 full [0,32); batch passed for output indexing.
__global__ __launch_bounds__(256, 2)
void attn_mfma(const u16* __restrict__ qkvh,
               const float* __restrict__ rpb,
               u16* __restrict__ outb, int batch)
{
    __shared__ __align__(16) u16 stg[3 * 64 * 64];
    __shared__ __align__(16) u16 Pl[4][64][68];
    __shared__ float rpl[900];
    __shared__ float linv[4][64];
    __shared__ __align__(16) u16 zlds[8];

    const int bid = blockIdx.x;            // 4096 = 1024 windows x 4 head-quads
    const int hq  = bid & 3;
    const int mw  = bid >> 2;              // 0..1023
    const int i1  = mw >> 5, i3 = mw & 31;
    const int tid = threadIdx.x;
    const int wv  = tid >> 6, lane = tid & 63;
    const int l15 = lane & 15, l4 = lane >> 4;
    const size_t base = (size_t)i1 * 1572864 + (size_t)i3 * 6144 + (size_t)hq * 64;

    #pragma unroll
    for (int it = 0; it < 6; ++it) {
        const int id = it * 256 + tid;
        const int s = id >> 9, tok = (id >> 3) & 63, cd = id & 7;
        const int csrc = cd ^ (tok & 7);
        const int i2 = tok >> 3, i4 = tok & 7;
        const u16* src = qkvh + base + (size_t)i2 * 196608 + (size_t)i4 * 768 +
                         s * 256 + csrc * 8;
        GLDS16(src, &stg[(it * 256 + wv * 64) * 8]);
    }
    for (int i = tid; i < 900; i += 256)
        rpl[i] = rpb[(i >> 2) * 16 + hq * 4 + (i & 3)];
    if (tid < 8) zlds[tid] = 0;
    __syncthreads();

    f32x4 acc[4][4];
    #pragma unroll
    for (int kt = 0; kt < 4; ++kt)
        #pragma unroll
        for (int qt = 0; qt < 4; ++qt)
            acc[kt][qt] = (f32x4){0.f, 0.f, 0.f, 0.f};

    bf16x8 ka[4], qb[4];
    #pragma unroll
    for (int kt = 0; kt < 4; ++kt) {
        const int tok = kt * 16 + l15;
        const int phys = (2 * wv + l4) ^ (tok & 7);
        const u16* p = (l4 < 2) ? &stg[(64 + tok) * 64 + phys * 8] : zlds;
        ka[kt] = *(const bf16x8*)p;
    }
    #pragma unroll
    for (int qt = 0; qt < 4; ++qt) {
        const int tok = qt * 16 + l15;
        const int phys = (2 * wv + l4) ^ (tok & 7);
        const u16* p = (l4 < 2) ? &stg[tok * 64 + phys * 8] : zlds;
        qb[qt] = *(const bf16x8*)p;
    }
    #pragma unroll
    for (int kt = 0; kt < 4; ++kt)
        #pragma unroll
        for (int qt = 0; qt < 4; ++qt)
            acc[kt][qt] = __builtin_amdgcn_mfma_f32_16x16x32_bf16(
                ka[kt], qb[qt], acc[kt][qt], 0, 0, 0);

    #pragma unroll
    for (int qt = 0; qt < 4; ++qt) {
        const int q = qt * 16 + l15;
        const int base_q = ((q >> 3) + 7) * 15 + (q & 7) + 7;
        #pragma unroll
        for (int kt = 0; kt < 4; ++kt) {
            const int koff = kt * 30 + (l4 >> 1) * 15 + (l4 & 1) * 4;
            #pragma unroll
            for (int r = 0; r < 4; ++r)
                acc[kt][qt][r] = acc[kt][qt][r] * 0.25f +
                                 rpl[(base_q - koff - r) * 4 + wv];
        }
        float mx = -1e30f;
        #pragma unroll
        for (int kt = 0; kt < 4; ++kt)
            #pragma unroll
            for (int r = 0; r < 4; ++r)
                mx = fmaxf(mx, acc[kt][qt][r]);
        mx = fmaxf(mx, __shfl_xor(mx, 16));
        mx = fmaxf(mx, __shfl_xor(mx, 32));
        float l = 0.f;
        #pragma unroll
        for (int kt = 0; kt < 4; ++kt)
            #pragma unroll
            for (int r = 0; r < 4; ++r) {
                const float p = __expf(acc[kt][qt][r] - mx);
                acc[kt][qt][r] = p;
                l += p;
            }
        l += __shfl_xor(l, 16);
        l += __shfl_xor(l, 32);
        if (l4 == 0) linv[wv][q] = 1.f / l;
        #pragma unroll
        for (int kt = 0; kt < 4; ++kt) {
            const int ku = kt * 16 + l4 * 4;
            const unsigned w0 = (unsigned)f2bf(acc[kt][qt][0]) |
                                ((unsigned)f2bf(acc[kt][qt][1]) << 16);
            const unsigned w1 = (unsigned)f2bf(acc[kt][qt][2]) |
                                ((unsigned)f2bf(acc[kt][qt][3]) << 16);
            *(unsigned*)&Pl[wv][q][ku]     = w0;
            *(unsigned*)&Pl[wv][q][ku + 2] = w1;
        }
    }

    f32x4 oac[4];
    #pragma unroll
    for (int qt = 0; qt < 4; ++qt) oac[qt] = (f32x4){0.f, 0.f, 0.f, 0.f};

    #pragma unroll
    for (int ks = 0; ks < 2; ++ks) {
        bf16x8 vf;
        #pragma unroll
        for (int e = 0; e < 8; ++e) {
            const int tok = ks * 32 + l4 * 8 + e;
            const int phys = (2 * wv + (l15 >> 3)) ^ e;
            vf[e] = *(const __bf16*)&stg[(128 + tok) * 64 + phys * 8 + (l15 & 7)];
        }
        #pragma unroll
        for (int qt = 0; qt < 4; ++qt) {
            const int q = qt * 16 + l15;
            const uint2 a  = *(const uint2*)&Pl[wv][q][ks * 32 + l4 * 8];
            const uint2 b2 = *(const uint2*)&Pl[wv][q][ks * 32 + l4 * 8 + 4];
            uint4 t4; t4.x = a.x; t4.y = a.y; t4.z = b2.x; t4.w = b2.y;
            const bf16x8 pf = *(const bf16x8*)&t4;
            oac[qt] = __builtin_amdgcn_mfma_f32_16x16x32_bf16(pf, vf, oac[qt], 0, 0, 0);
        }
    }

    const int head = hq * 4 + wv;
    const int n = batch * 1024 + i1 * 32 + i3;
    u16* op = outb + ((size_t)(n * 16 + head) << 10);
    #pragma unroll
    for (int qt = 0; qt < 4; ++qt)
        #pragma unroll
        for (int r = 0; r < 4; ++r) {
            const int q = qt * 16 + l4 * 4 + r;
            op[q * 16 + l15] = f2bf(oac[qt][r] * linv[wv][q]);
        }
}

// ---------------------------------------------------------------------------
// Staging helper: load 39x71 ext tile (ext: 256->254, outside->0) into LDS
// with vectorized interior (39x8 uint4 chunks) + scalar 7-col halo.
template <int STRIDE>
__device__ __forceinline__ void stage_ext_tile(const u16* __restrict__ A,
                                               float (*S)[STRIDE],
                                               int TH, int TW, int tid)
{
    for (int idx = tid; idx < 312; idx += 256) {
        const int i = idx >> 3, ch = idx & 7;
        const int gh = TH + i - 3;
        const int eh = (gh == 256) ? 254 : gh;
        float f[8];
        if ((unsigned)eh < 256u) {
            const uint4 u = *(const uint4*)(A + eh * 256 + TW + ch * 8);
            unp8(u, f);
        } else {
            #pragma unroll
            for (int e = 0; e < 8; ++e) f[e] = 0.f;
        }
        #pragma unroll
        for (int e = 0; e < 8; ++e) S[i][3 + ch * 8 + e] = f[e];
    }
    for (int idx = tid; idx < 273; idx += 256) {
        const int i = idx / 7, jj = idx - i * 7;
        const int j = (jj < 3) ? jj : jj + 64;
        const int gh = TH + i - 3, gw = TW + j - 3;
        const int eh = (gh == 256) ? 254 : gh;
        const int ew = (gw == 256) ? 254 : gw;
        float v = 0.f;
        if ((unsigned)eh < 256u && (unsigned)ew < 256u) v = bf2f(A[eh * 256 + ew]);
        S[i][j] = v;
    }
}

// ---------------------------------------------------------------------------
// pool_add2: outsum = 0.125*(V8+H8)(attn_ext) + local, one 32x64 tile/block.
__global__ __launch_bounds__(256)
void pool_add2(const u16* __restrict__ attn,
               const u16* __restrict__ local,
               u16* __restrict__ outsum)
{
    __shared__ float Sa[39][73];
    __shared__ float Sv[32][65];

    const int bid   = blockIdx.x;
    const int plane = bid >> 5;
    const int tile  = bid & 31;
    const int TH    = (tile >> 2) * 32;
    const int TW    = (tile & 3) * 64;
    const int tid   = threadIdx.x;
    const u16* A    = attn + (size_t)plane * HWPIX;

    stage_ext_tile<73>(A, Sa, TH, TW, tid);
    __syncthreads();

    {
        const int c = tid & 63, g = tid >> 6;
        float s = 0.f;
        #pragma unroll
        for (int t = 0; t < 8; ++t) s += Sa[8 * g + t][c + 3];
        #pragma unroll
        for (int q = 0; q < 8; ++q) {
            Sv[8 * g + q][c] = s;
            if (q < 7) s += Sa[8 * g + q + 8][c + 3] - Sa[8 * g + q][c + 3];
        }
    }
    __syncthreads();

    {
        const int r = tid >> 3, cb = tid & 7;
        float h = 0.f;
        #pragma unroll
        for (int t = 0; t < 8; ++t) h += Sa[r + 3][8 * cb + t];
        const uint4 lv = *(const uint4*)(local + (size_t)plane * HWPIX +
                                         (TH + r) * 256 + TW + 8 * cb);
        float lf[8];
        unp8(lv, lf);
        u16 res[8];
        #pragma unroll
        for (int q = 0; q < 8; ++q) {
            const int ox = 8 * cb + q;
            res[q] = f2bf(0.125f * (Sv[r][ox] + h) + lf[q]);
            if (q < 7) h += Sa[r + 3][ox + 8] - Sa[r + 3][ox];
        }
        uint4 pk;
        pk.x = (unsigned)res[0] | ((unsigned)res[1] << 16);
        pk.y = (unsigned)res[2] | ((unsigned)res[3] << 16);
        pk.z = (unsigned)res[4] | ((unsigned)res[5] << 16);
        pk.w = (unsigned)res[6] | ((unsigned)res[7] << 16);
        *(uint4*)(outsum + (size_t)plane * HWPIX + (TH + r) * 256 + TW + 8 * cb) = pk;
    }
}

// ---------------------------------------------------------------------------
// dwconv3: reflect(0,1)+zero-pad(3) + depthwise 8x8, register-blocked 2x4.
__global__ __launch_bounds__(256)
void dwconv3(const u16* __restrict__ outsum, const float* __restrict__ wdw,
             u16* __restrict__ dwo)
{
    __shared__ __align__(16) float Sp[39][76];
    __shared__ float wk[64];

    const int bid   = blockIdx.x;
    const int plane = bid >> 5;
    const int c     = plane & 255;
    const int tile  = bid & 31;
    const int TH    = (tile >> 2) * 32;
    const int TW    = (tile & 3) * 64;
    const int tid   = threadIdx.x;
    const u16* A    = outsum + (size_t)plane * HWPIX;

    if (tid < 64) wk[tid] = wdw[c * 64 + tid];

    stage_ext_tile<76>(A, Sp, TH, TW, tid);
    __syncthreads();

    float wreg[64];
    #pragma unroll
    for (int i = 0; i < 64; ++i) wreg[i] = wk[i];

    const int rb = tid >> 4;
    const int cb = tid & 15;
    const int oy2 = rb * 2, ox4 = cb * 4;
    float acc[2][4];
    #pragma unroll
    for (int q = 0; q < 2; ++q)
        #pragma unroll
        for (int j = 0; j < 4; ++j) acc[q][j] = 0.f;

    #pragma unroll
    for (int r = 0; r < 9; ++r) {
        const float4 ra  = *(const float4*)&Sp[oy2 + r][ox4];
        const float4 rb4 = *(const float4*)&Sp[oy2 + r][ox4 + 4];
        const float4 rc  = *(const float4*)&Sp[oy2 + r][ox4 + 8];
        const float row[12] = {ra.x, ra.y, ra.z, ra.w, rb4.x, rb4.y, rb4.z, rb4.w,
                               rc.x, rc.y, rc.z, rc.w};
        #pragma unroll
        for (int q = 0; q < 2; ++q) {
            const int kh = r - q;
            if (kh >= 0 && kh < 8) {
                #pragma unroll
                for (int kw = 0; kw < 8; ++kw) {
                    const float w = wreg[kh * 8 + kw];
                    #pragma unroll
                    for (int j = 0; j < 4; ++j)
                        acc[q][j] += w * row[j + kw];
                }
            }
        }
    }
    u16* O = dwo + (size_t)plane * HWPIX;
    #pragma unroll
    for (int q = 0; q < 2; ++q) {
        ushort4 pk;
        pk.x = f2bf(acc[q][0]); pk.y = f2bf(acc[q][1]);
        pk.z = f2bf(acc[q][2]); pk.w = f2bf(acc[q][3]);
        *(ushort4*)&O[(TH + oy2 + q) * 256 + TW + ox4] = pk;
    }
}

// ---------------------------------------------------------------------------
extern "C" void kernel_launch(void* const* d_in, const int* in_sizes, int n_in,
                              void* d_out, int out_size, void* d_ws, size_t ws_size,
                              hipStream_t stream)
{
    const float* x     = (const float*)d_in[0];
    const float* w_qkv = (const float*)d_in[1];
    const float* w_l1  = (const float*)d_in[2];
    const float* bn1g  = (const float*)d_in[3];
    const float* bn1b  = (const float*)d_in[4];
    const float* w_l2  = (const float*)d_in[5];
    const float* bn2g  = (const float*)d_in[6];
    const float* bn2b  = (const float*)d_in[7];
    const float* w_dw  = (const float*)d_in[8];
    const float* bn3g  = (const float*)d_in[9];
    const float* bn3b  = (const float*)d_in[10];
    const float* w_pw  = (const float*)d_in[11];
    const float* rpb   = (const float*)d_in[12];
    float* out = (float*)d_out;
    char* ws = (char*)d_ws;

    if (ws_size < (size_t)236587520) return;

    u16* x_t = (u16*)(ws + 0);
    u16* dwt = (u16*)(ws + 0);
    u16* qkvh   = (u16*)(ws + 67108864);     // per-batch [768][65536] bf16 = 96MiB
    u16* outsum = (u16*)(ws + 67108864);
    u16* localb  = (u16*)(ws + 167772160);
    u16* dw_nchw = (u16*)(ws + 167772160);
    u16*   wl      = (u16*)(ws + 234881024);
    u16*   wq      = (u16*)(ws + 236060672);
    u16*   wpw     = (u16*)(ws + 236453888);
    float* bias_l  = (float*)(ws + 236584960);
    float* bias_pw = (float*)(ws + 236585984);
    u16*   zeros   = (u16*)(ws + 236587008);
    u16* attnb = (u16*)d_out;              // d_out as bf16 attn scratch

    prep_weights<<<1024, 256, 0, stream>>>(w_qkv, w_l1, bn1g, bn1b, w_l2, bn2g, bn2b,
                                           w_pw, bn3g, bn3b, wl, wq, wpw, bias_l, bias_pw, zeros);
    to_chlast_f32<<<NPIX / 64, 256, 0, stream>>>(x, x_t);
    // conv3x3 + bias (4-phase 256² structure)
    conv8<9, true, true, false><<<dim3(NPIX / 256, 1), 512, 0, stream>>>(
        x_t, wl, bias_l, localb, zeros, 0);
    // qkv batch 0: full 768 oc into region B, then attention for batch 0
    conv8<1, true, false, true><<<dim3(HWPIX / 256, 3), 512, 0, stream>>>(
        x_t, wq, nullptr, qkvh, zeros, 0);
    attn_mfma<<<4096, 256, 0, stream>>>(qkvh, rpb, attnb, 0);
    // qkv batch 1, attention batch 1
    conv8<1, true, false, true><<<dim3(HWPIX / 256, 3), 512, 0, stream>>>(
        x_t, wq, nullptr, qkvh, zeros, HWPIX);
    attn_mfma<<<4096, 256, 0, stream>>>(qkvh, rpb, attnb, 1);
    // pools + local add -> bf16 outsum (overwrites qkv region)
    pool_add2<<<16384, 256, 0, stream>>>(attnb, localb, outsum);
    dwconv3<<<16384, 256, 0, stream>>>(outsum, w_dw, dw_nchw);
    to_chlast_bf16<<<NPIX / 64, 256, 0, stream>>>(dw_nchw, dwt);
    // pointwise + bias -> final f32 output
    conv8<1, false, true, false><<<dim3(NPIX / 256, 1), 512, 0, stream>>>(
        dwt, wpw, bias_pw, out, zeros, 0);
}